// Round 13
// baseline (183.533 us; speedup 1.0000x reference)
//
#include <hip/hip_runtime.h>
#include <hip/hip_bf16.h>

typedef unsigned short u16;
typedef unsigned int u32;
typedef __attribute__((ext_vector_type(8))) short bf16x8;
typedef __attribute__((ext_vector_type(4))) float f32x4;

#define MFMA_BF16(a, b, c) __builtin_amdgcn_mfma_f32_16x16x32_bf16((a), (b), (c), 0, 0, 0)

__device__ __forceinline__ u16 f2bf(float f) {
    u32 u;
    __builtin_memcpy(&u, &f, 4);
    u += 0x7fffu + ((u >> 16) & 1u);
    return (u16)(u >> 16);
}

__device__ __forceinline__ void glds16(const void* g, void* l) {
    __builtin_amdgcn_global_load_lds(
        (__attribute__((address_space(1))) void*)(g),
        (__attribute__((address_space(3))) void*)(l),
        16, 0, 0);
}

// ---------------------------------------------------------------------------
// Fused input prep (ONE launch):
//   blocks [0,2048):   f32 -> bf16 convert of x (8 elems/thread)
//   blocks [2048,2816): transpose+cvt c_attn_w f32[1024][3072] -> bf16[3072][1024]
//   blocks [2816,3072): transpose+cvt c_proj_w f32[1024][1024] -> bf16[1024][1024]
// ---------------------------------------------------------------------------
__global__ __launch_bounds__(256) void prep(const float* __restrict__ x,
                                            u16* __restrict__ xb,
                                            const float* __restrict__ aw,
                                            u16* __restrict__ awt,
                                            const float* __restrict__ pw,
                                            u16* __restrict__ pwt) {
    __shared__ u16 tl[64][68];
    const int tid = threadIdx.x;
    const int f = blockIdx.x;

    if (f < 2048) {                       // x f32 -> bf16
        const int i = f * 256 + tid;
        const float4* p = (const float4*)x;
        float4 a = p[i * 2], b = p[i * 2 + 1];
        ushort4 lo, hi;
        lo.x = f2bf(a.x); lo.y = f2bf(a.y); lo.z = f2bf(a.z); lo.w = f2bf(a.w);
        hi.x = f2bf(b.x); hi.y = f2bf(b.y); hi.z = f2bf(b.z); hi.w = f2bf(b.w);
        *(ushort4*)&xb[i * 8] = lo;
        *(ushort4*)&xb[i * 8 + 4] = hi;
        return;
    }

    // transpose part: pick matrix + tile coords
    const float* in;
    u16* out;
    int K, N, n0, k0;
    if (f < 2816) {
        in = aw; out = awt; K = 1024; N = 3072;
        const int t = f - 2048;
        n0 = (t % 48) * 64; k0 = (t / 48) * 64;
    } else {
        in = pw; out = pwt; K = 1024; N = 1024;
        const int t = f - 2816;
        n0 = (t & 15) * 64; k0 = (t >> 4) * 64;
    }
    #pragma unroll
    for (int it = 0; it < 4; ++it) {
        int idx = tid + it * 256;
        int r = idx >> 4, c4 = (idx & 15) * 4;
        float4 v = *(const float4*)&in[(size_t)(k0 + r) * N + n0 + c4];
        tl[r][c4 + 0] = f2bf(v.x); tl[r][c4 + 1] = f2bf(v.y);
        tl[r][c4 + 2] = f2bf(v.z); tl[r][c4 + 3] = f2bf(v.w);
    }
    __syncthreads();
    #pragma unroll
    for (int it = 0; it < 4; ++it) {
        int idx = tid + it * 256;
        int r = idx >> 4, c4 = (idx & 15) * 4;
        ushort4 v;
        v.x = tl[c4 + 0][r]; v.y = tl[c4 + 1][r];
        v.z = tl[c4 + 2][r]; v.w = tl[c4 + 3][r];
        *(ushort4*)&out[(size_t)(n0 + r) * K + k0 + c4] = v;
    }
}

// ---------------------------------------------------------------------------
// QKV GEMM, 2-phase double-buffered: C = x @ c_attn_w^T + bias.
// K and Q bands (coln < 2048) -> kq COMPACT [4096][2048] (V band not stored).
// V band (coln >= 2048) -> vtr [BH][64][2048] TRANSPOSED DIRECTLY.
// BM=BN=128, BK=32, 4 waves 2x2; glds16 prefetch next K-tile BEFORE compute,
// ONE barrier/iter; LDS chunk swizzle (pre-swizzled source, rule 21).
// K cols (<1024) pre-scaled by log2(e)/sqrt(64). LDS 32 KB.
// ---------------------------------------------------------------------------
__global__ __launch_bounds__(256) void gemm_qkv(const u16* __restrict__ A,
                                                const u16* __restrict__ BT,
                                                const float* __restrict__ bias,
                                                u16* __restrict__ out,
                                                u16* __restrict__ vtr) {
    __shared__ u16 As[2][128 * 32];
    __shared__ u16 Bs[2][128 * 32];
    const int tid = threadIdx.x;
    const int w = tid >> 6, lane = tid & 63;
    const int c = lane & 15, qd = lane >> 4;
    const int wm = (w >> 1) * 64, wn = (w & 1) * 64;
    const int bm = blockIdx.x * 128, bn = blockIdx.y * 128;
    const int K = 1024;

    f32x4 acc[4][4];
    #pragma unroll
    for (int mt = 0; mt < 4; ++mt)
        #pragma unroll
        for (int nt = 0; nt < 4; ++nt)
            acc[mt][nt] = (f32x4){0.f, 0.f, 0.f, 0.f};

    // staging: thread -> (row = tid>>2 [+64], src chunk swizzled by (row>>1)&3)
    const int srow = tid >> 2;
    const int schk8 = ((tid & 3) ^ ((tid >> 3) & 3)) * 8;
    const u16* aP = A + (size_t)(bm + srow) * K + schk8;
    const u16* bP = BT + (size_t)(bn + srow) * K + schk8;
    const int rk = (c >> 1) & 3;          // read-side xor key

    // prologue: stage K-tile 0 into buffer 0
    glds16(aP, &As[0][tid * 8]);
    glds16(aP + 64 * K, &As[0][2048 + tid * 8]);
    glds16(bP, &Bs[0][tid * 8]);
    glds16(bP + 64 * K, &Bs[0][2048 + tid * 8]);
    __syncthreads();

    for (int kk = 0; kk < K; kk += 32) {
        const int cur = (kk >> 5) & 1;
        if (kk + 32 < K) {               // prefetch next K-tile into other buf
            const int nb = cur ^ 1;
            glds16(aP + kk + 32, &As[nb][tid * 8]);
            glds16(aP + kk + 32 + 64 * K, &As[nb][2048 + tid * 8]);
            glds16(bP + kk + 32, &Bs[nb][tid * 8]);
            glds16(bP + kk + 32 + 64 * K, &Bs[nb][2048 + tid * 8]);
        }
        bf16x8 af[4], bfr[4];
        #pragma unroll
        for (int mt = 0; mt < 4; ++mt)
            af[mt] = *(const bf16x8*)&As[cur][(wm + mt * 16 + c) * 32 + ((qd ^ rk) << 3)];
        #pragma unroll
        for (int nt = 0; nt < 4; ++nt)
            bfr[nt] = *(const bf16x8*)&Bs[cur][(wn + nt * 16 + c) * 32 + ((qd ^ rk) << 3)];
        #pragma unroll
        for (int mt = 0; mt < 4; ++mt)
            #pragma unroll
            for (int nt = 0; nt < 4; ++nt)
                acc[mt][nt] = MFMA_BF16(af[mt], bfr[nt], acc[mt][nt]);
        __syncthreads();                 // drains prefetch vmcnt + read lgkm
    }

    #pragma unroll
    for (int nt = 0; nt < 4; ++nt) {
        const int coln = bn + wn + nt * 16 + c;
        const float bv = bias[coln];
        if (coln < 2048) {
            // K band pre-scaled by log2(e)/sqrt(64); Q band natural
            const float kscl = (coln < 1024) ? 0.18033688f : 1.0f;
            #pragma unroll
            for (int mt = 0; mt < 4; ++mt)
                #pragma unroll
                for (int r = 0; r < 4; ++r) {
                    const int row = bm + wm + mt * 16 + qd * 4 + r;
                    out[(size_t)row * 2048 + coln] = f2bf((acc[mt][nt][r] + bv) * kscl);
                }
        } else {
            // V band: write transposed directly into vtr[bh][dd][t]
            const int hh = (coln - 2048) >> 6;
            const int dd = coln & 63;
            #pragma unroll
            for (int mt = 0; mt < 4; ++mt) {
                const int row0 = bm + wm + mt * 16 + qd * 4;
                const int bb = row0 >> 11, t0 = row0 & 2047;
                ushort4 st;
                st.x = f2bf(acc[mt][nt][0] + bv);
                st.y = f2bf(acc[mt][nt][1] + bv);
                st.z = f2bf(acc[mt][nt][2] + bv);
                st.w = f2bf(acc[mt][nt][3] + bv);
                *(ushort4*)&vtr[((size_t)(bb * 16 + hh) * 64 + dd) * 2048 + t0] = st;
            }
        }
    }
}

// ---------------------------------------------------------------------------
// Proj GEMM: C[4096,1024] f32 = A[4096,1024]*BT[1024,1024]^T + bias.
// BM=128, BN=64 -> grid 32x16 = 512 blocks. 4 waves 4Mx1N. LDS 24 KB.
// ---------------------------------------------------------------------------
__global__ __launch_bounds__(256) void gemm_proj(const u16* __restrict__ A,
                                                 const u16* __restrict__ BT,
                                                 const float* __restrict__ bias,
                                                 float* __restrict__ outf) {
    __shared__ u16 As[2][128 * 32];
    __shared__ u16 Bs[2][64 * 32];
    const int tid = threadIdx.x;
    const int w = tid >> 6, lane = tid & 63;
    const int c = lane & 15, qd = lane >> 4;
    const int wm = w * 32;
    const int bm = blockIdx.x * 128, bn = blockIdx.y * 64;
    const int K = 1024;

    f32x4 acc[2][4];
    #pragma unroll
    for (int mt = 0; mt < 2; ++mt)
        #pragma unroll
        for (int nt = 0; nt < 4; ++nt)
            acc[mt][nt] = (f32x4){0.f, 0.f, 0.f, 0.f};

    const int srow = tid >> 2;
    const int schk8 = ((tid & 3) ^ ((tid >> 3) & 3)) * 8;
    const u16* aP = A + (size_t)(bm + srow) * K + schk8;
    const u16* bP = BT + (size_t)(bn + srow) * K + schk8;
    const int rk = (c >> 1) & 3;

    glds16(aP, &As[0][tid * 8]);
    glds16(aP + 64 * K, &As[0][2048 + tid * 8]);
    glds16(bP, &Bs[0][tid * 8]);
    __syncthreads();

    for (int kk = 0; kk < K; kk += 32) {
        const int cur = (kk >> 5) & 1;
        if (kk + 32 < K) {
            const int nb = cur ^ 1;
            glds16(aP + kk + 32, &As[nb][tid * 8]);
            glds16(aP + kk + 32 + 64 * K, &As[nb][2048 + tid * 8]);
            glds16(bP + kk + 32, &Bs[nb][tid * 8]);
        }
        bf16x8 af[2], bfr[4];
        #pragma unroll
        for (int mt = 0; mt < 2; ++mt)
            af[mt] = *(const bf16x8*)&As[cur][(wm + mt * 16 + c) * 32 + ((qd ^ rk) << 3)];
        #pragma unroll
        for (int nt = 0; nt < 4; ++nt)
            bfr[nt] = *(const bf16x8*)&Bs[cur][(nt * 16 + c) * 32 + ((qd ^ rk) << 3)];
        #pragma unroll
        for (int mt = 0; mt < 2; ++mt)
            #pragma unroll
            for (int nt = 0; nt < 4; ++nt)
                acc[mt][nt] = MFMA_BF16(af[mt], bfr[nt], acc[mt][nt]);
        __syncthreads();
    }

    #pragma unroll
    for (int nt = 0; nt < 4; ++nt) {
        const int coln = bn + nt * 16 + c;
        const float bv = bias[coln];
        #pragma unroll
        for (int mt = 0; mt < 2; ++mt)
            #pragma unroll
            for (int r = 0; r < 4; ++r) {
                const int row = bm + wm + mt * 16 + qd * 4 + r;
                outf[(size_t)row * 1024 + coln] = acc[mt][nt][r] + bv;
            }
    }
}

// ---------------------------------------------------------------------------
// MFMA flash attention v13: PV LAGGED ONE TILE behind QK^T.
// v6 diagnosis: per-tile serial chain qf->QK->exp2->pack->Ps->pf->PV->barrier
// (~520cy) with only 3-way TLP; PV(j) has NO dependence on QK(j+1), yet sat
// serially appended. v13: at tile j compute QK(j) AND PV(j-1) — independent,
// scheduler interleaves PV's pf/vf/MFMA under the qf->QK->exp chain.
// Correctness structure:
//  - V TRIPLE-buffer (rolling vprev/vcur/vnext): PV(j-1) reads Vb[vprev];
//    V(j+1) stages into Vb[vnext]; any buffer's re-stage is separated from
//    its last read by the end-of-tile barrier. ONE barrier/tile kept.
//  - Ps single wave-private buffer: pf read (tile j-1) precedes tile-j pack
//    write in program order (WAR handled by compiler lgkmcnt).
//  - Trailing PV after the loop; j=0 skips PV.
// LDS = Qb 16K + Vb 24K + Ps 9.2K + red = 50.4 KB -> 3 blocks/CU retained.
// Everything else (K-frags in regs, static-max softmax, v_perm pack,
// XCD-grouped decode, longest-first, epilogue) = v6 verbatim.
// ---------------------------------------------------------------------------
__global__ __launch_bounds__(256, 3) void attn_kernel(const u16* __restrict__ kq,
                                                      const u16* __restrict__ vtbuf,
                                                      u16* __restrict__ outb) {
    __shared__ __align__(16) u16 Qb[2][64 * 64];
    __shared__ __align__(16) u16 Vb[3][64 * 64];
    __shared__ __align__(16) u16 Ps[4][16 * 72];
    __shared__ float red[4][16];

    const int tid = threadIdx.x;
    const int w = tid >> 6, lane = tid & 63;
    const int c = lane & 15, qd = lane >> 4;
    // decode: xcd = f&7 hosts bh in [xcd*4, xcd*4+4); ib descending in time
    const int f = blockIdx.x;
    const int bh = (f & 7) * 4 + ((f >> 3) & 3);
    const int ib = 31 - (f >> 5);       // longest blocks dispatch first
    const int b = bh >> 4, hh = bh & 15;
    const u16* kp = kq + (size_t)b * 2048 * 2048 + hh * 64;          // k band
    const u16* qp = kq + (size_t)b * 2048 * 2048 + 1024 + hh * 64;   // q band
    const u16* vp = vtbuf + (size_t)bh * (64 * 2048);
    u16* op = outb + (size_t)b * (2048 * 1024) + hh * 64;
    const f32x4 zero4 = {0.f, 0.f, 0.f, 0.f};

    // staging geometry: thread covers slots (w*128+lane) and (+64)
    const int slot0 = w * 128 + lane;
    const int slot1 = slot0 + 64;
    const int r0 = slot0 >> 3, r1 = slot1 >> 3;            // r1 = r0 + 8
    const int c8g = ((lane & 7) ^ ((lane >> 3) & 7)) * 8;  // swizzled src col
    const int swz = (c & 7);                               // read-side xor key

    const int nj = ib + 1;
    const int iw = ib * 64 + w * 16;                       // wave's 16 i-rows

    // K fragments direct from global (2 KB/wave, read once per block)
    bf16x8 kf[2];
    #pragma unroll
    for (int kt = 0; kt < 2; ++kt)
        kf[kt] = *(const bf16x8*)&kp[(size_t)(iw + c) * 2048 + kt * 32 + qd * 8];

    f32x4 oacc[4];
    #pragma unroll
    for (int nt = 0; nt < 4; ++nt)
        oacc[nt] = zero4;
    float l_lane = 0.f;

    // prologue: stage tile 0 (Q -> Qb[0], V -> Vb[0])
    glds16(qp + (size_t)r0 * 2048 + c8g, &Qb[0][slot0 * 8]);
    glds16(qp + (size_t)r1 * 2048 + c8g, &Qb[0][slot1 * 8]);
    glds16(vp + (size_t)r0 * 2048 + c8g, &Vb[0][slot0 * 8]);
    glds16(vp + (size_t)r1 * 2048 + c8g, &Vb[0][slot1 * 8]);
    __syncthreads();

    int qcur = 0;                      // Qb index of current tile
    int vprev = 2, vcur = 0, vnext = 1; // Vb rolling indices

    for (int jj = 0; jj < nj; ++jj) {
        if (jj + 1 < nj) {              // async-prefetch next tile
            const int jn = (jj + 1) * 64;
            glds16(qp + (size_t)(jn + r0) * 2048 + c8g, &Qb[qcur ^ 1][slot0 * 8]);
            glds16(qp + (size_t)(jn + r1) * 2048 + c8g, &Qb[qcur ^ 1][slot1 * 8]);
            glds16(vp + (size_t)r0 * 2048 + jn + c8g, &Vb[vnext][slot0 * 8]);
            glds16(vp + (size_t)r1 * 2048 + jn + c8g, &Vb[vnext][slot1 * 8]);
        }
        const int j0 = jj * 64;

        // S^T[j][i]: A = Q rows j (4 jt), B = kf (wave's 16 i-rows)
        bf16x8 qf[4][2];
        #pragma unroll
        for (int jt = 0; jt < 4; ++jt)
            #pragma unroll
            for (int kt = 0; kt < 2; ++kt)
                qf[jt][kt] = *(const bf16x8*)&Qb[qcur][(jt * 16 + c) * 64 + (((kt * 4 + qd) ^ swz) << 3)];
        f32x4 sacc[4];
        #pragma unroll
        for (int jt = 0; jt < 4; ++jt) {
            f32x4 s0 = zero4;
            s0 = MFMA_BF16(qf[jt][0], kf[0], s0);
            s0 = MFMA_BF16(qf[jt][1], kf[1], s0);
            sacc[jt] = s0;
        }

        // PV for tile jj-1 — independent of QK(jj); reads Ps (written last
        // tile, same wave) and Vb[vprev] (re-staged only after next barrier).
        if (jj > 0) {
            #pragma unroll
            for (int kt = 0; kt < 2; ++kt) {
                bf16x8 pf = *(const bf16x8*)&Ps[w][c * 72 + kt * 32 + qd * 8];
                #pragma unroll
                for (int nt = 0; nt < 4; ++nt) {
                    bf16x8 vf = *(const bf16x8*)&Vb[vprev][(nt * 16 + c) * 64 + (((kt * 4 + qd) ^ swz) << 3)];
                    oacc[nt] = MFMA_BF16(pf, vf, oacc[nt]);
                }
            }
        }

        if (j0 + 63 > iw) {   // causal: valid iff j <= i
            #pragma unroll
            for (int jt = 0; jt < 4; ++jt)
                #pragma unroll
                for (int r = 0; r < 4; ++r) {
                    int j = j0 + jt * 16 + qd * 4 + r;
                    int i = iw + c;
                    if (j > i) sacc[jt][r] = -3.0e38f;
                }
        }

        // static-max softmax; pack P via round-half-up + v_perm; write AFTER
        // the PV reads above (program order -> WAR on Ps is safe).
        #pragma unroll
        for (int jt = 0; jt < 4; ++jt) {
            float p0 = exp2f(sacc[jt][0]);
            float p1 = exp2f(sacc[jt][1]);
            float p2 = exp2f(sacc[jt][2]);
            float p3 = exp2f(sacc[jt][3]);
            l_lane += (p0 + p1) + (p2 + p3);
            u32 b0, b1, b2, b3;
            __builtin_memcpy(&b0, &p0, 4);
            __builtin_memcpy(&b1, &p1, 4);
            __builtin_memcpy(&b2, &p2, 4);
            __builtin_memcpy(&b3, &p3, 4);
            uint2 pk;
            pk.x = __builtin_amdgcn_perm(b1 + 0x8000u, b0 + 0x8000u, 0x07060302u);
            pk.y = __builtin_amdgcn_perm(b3 + 0x8000u, b2 + 0x8000u, 0x07060302u);
            *(uint2*)&Ps[w][c * 72 + jt * 16 + qd * 4] = pk;
        }

        __syncthreads();   // drains prefetch glds; separates all buffer reads
                           // (Qb[qcur], Vb[vprev]) from their next re-stage
        qcur ^= 1;
        vprev = vcur; vcur = vnext; vnext = (vnext == 2) ? 0 : vnext + 1;
    }

    // trailing PV for the last tile (Ps + Vb[vprev] stable; no more staging)
    #pragma unroll
    for (int kt = 0; kt < 2; ++kt) {
        bf16x8 pf = *(const bf16x8*)&Ps[w][c * 72 + kt * 32 + qd * 8];
        #pragma unroll
        for (int nt = 0; nt < 4; ++nt) {
            bf16x8 vf = *(const bf16x8*)&Vb[vprev][(nt * 16 + c) * 64 + (((kt * 4 + qd) ^ swz) << 3)];
            oacc[nt] = MFMA_BF16(pf, vf, oacc[nt]);
        }
    }

    // epilogue: reduce l over qd, redistribute per-row, write out
    float l = l_lane;
    l += __shfl_xor(l, 16);
    l += __shfl_xor(l, 32);
    red[w][c] = l;
    #pragma unroll
    for (int r = 0; r < 4; ++r) {
        const int irow = iw + qd * 4 + r;
        const float inv = 1.0f / red[w][qd * 4 + r];
        #pragma unroll
        for (int nt = 0; nt < 4; ++nt)
            op[(size_t)irow * 1024 + nt * 16 + c] = f2bf(oacc[nt][r] * inv);
    }
}

// ---------------------------------------------------------------------------
// ws plan (peak 34 MiB, ALL LIFETIMES DISJOINT):
//   kq@0       16M  [4096][2048] bf16 (K+Q compact)   live gemm_qkv -> attn
//   vtr@16M     8M  [BH][64][2048]                    live gemm_qkv -> attn
//   wt_attn@24M 6M                                    live prep -> gemm_qkv
//   abuf@24M    8M  (overlaps wt_attn AFTER it's dead) live attn -> gemm_proj
//   wt_proj@32M 2M  (own slot, untouched in between)  live prep -> gemm_proj
//   xb (bf16 x) staged in d_out (16 MB f32 out); dead before gemm_proj.
// ---------------------------------------------------------------------------
extern "C" void kernel_launch(void* const* d_in, const int* in_sizes, int n_in,
                              void* d_out, int out_size, void* d_ws, size_t ws_size,
                              hipStream_t stream) {
    const void *px = nullptr, *paw = nullptr, *pab = nullptr, *ppw = nullptr, *ppb = nullptr;
    for (int i = 0; i < n_in; ++i) {
        switch (in_sizes[i]) {
            case 4194304: px  = d_in[i]; break;  // x [2,2048,1024] f32
            case 3145728: paw = d_in[i]; break;  // c_attn_w [1024,3072] f32
            case 3072:    pab = d_in[i]; break;  // c_attn_b f32
            case 1048576: ppw = d_in[i]; break;  // c_proj_w [1024,1024] f32
            case 1024:    ppb = d_in[i]; break;  // c_proj_b f32
        }
    }
    if (!px || !paw || !pab || !ppw || !ppb) return;

    char* ws = (char*)d_ws;
    u16* kq      = (u16*)(ws);                 // [4096,2048] bf16  16 MB
    u16* vtr     = (u16*)(ws + 16777216);      // [2,16,64,2048]     8 MB
    u16* wt_attn = (u16*)(ws + 25165824);      // [3072,1024]        6 MB
    u16* abuf    = (u16*)(ws + 25165824);      // [4096,1024] bf16   8 MB (wt_attn dead)
    u16* wt_proj = (u16*)(ws + 33554432);      // [1024,1024]        2 MB (own slot)
    float* out   = (float*)d_out;              // [4096,1024] f32
    u16* xb      = (u16*)d_out;                // bf16 x staged in d_out

    prep<<<3072, 256, 0, stream>>>((const float*)px, xb,
                                   (const float*)paw, wt_attn,
                                   (const float*)ppw, wt_proj);
    gemm_qkv<<<dim3(32, 24), 256, 0, stream>>>(xb, wt_attn, (const float*)pab, kq, vtr);
    attn_kernel<<<dim3(1024), 256, 0, stream>>>(kq, vtr, abuf);
    gemm_proj<<<dim3(32, 16), 256, 0, stream>>>(abuf, wt_proj, (const float*)ppb, out);
}

// Round 14
// 177.995 us; speedup vs baseline: 1.0311x; 1.0311x over previous
//
#include <hip/hip_runtime.h>
#include <hip/hip_bf16.h>

typedef unsigned short u16;
typedef unsigned int u32;
typedef __attribute__((ext_vector_type(8))) short bf16x8;
typedef __attribute__((ext_vector_type(4))) float f32x4;

#define MFMA_BF16(a, b, c) __builtin_amdgcn_mfma_f32_16x16x32_bf16((a), (b), (c), 0, 0, 0)

__device__ __forceinline__ u16 f2bf(float f) {
    u32 u;
    __builtin_memcpy(&u, &f, 4);
    u += 0x7fffu + ((u >> 16) & 1u);
    return (u16)(u >> 16);
}

__device__ __forceinline__ void glds16(const void* g, void* l) {
    __builtin_amdgcn_global_load_lds(
        (__attribute__((address_space(1))) void*)(g),
        (__attribute__((address_space(3))) void*)(l),
        16, 0, 0);
}

// ---------------------------------------------------------------------------
// Fused input prep (ONE launch):
//   blocks [0,2048):   f32 -> bf16 convert of x (8 elems/thread)
//   blocks [2048,2816): transpose+cvt c_attn_w f32[1024][3072] -> bf16[3072][1024]
//   blocks [2816,3072): transpose+cvt c_proj_w f32[1024][1024] -> bf16[1024][1024]
// ---------------------------------------------------------------------------
__global__ __launch_bounds__(256) void prep(const float* __restrict__ x,
                                            u16* __restrict__ xb,
                                            const float* __restrict__ aw,
                                            u16* __restrict__ awt,
                                            const float* __restrict__ pw,
                                            u16* __restrict__ pwt) {
    __shared__ u16 tl[64][68];
    const int tid = threadIdx.x;
    const int f = blockIdx.x;

    if (f < 2048) {                       // x f32 -> bf16
        const int i = f * 256 + tid;
        const float4* p = (const float4*)x;
        float4 a = p[i * 2], b = p[i * 2 + 1];
        ushort4 lo, hi;
        lo.x = f2bf(a.x); lo.y = f2bf(a.y); lo.z = f2bf(a.z); lo.w = f2bf(a.w);
        hi.x = f2bf(b.x); hi.y = f2bf(b.y); hi.z = f2bf(b.z); hi.w = f2bf(b.w);
        *(ushort4*)&xb[i * 8] = lo;
        *(ushort4*)&xb[i * 8 + 4] = hi;
        return;
    }

    // transpose part: pick matrix + tile coords
    const float* in;
    u16* out;
    int K, N, n0, k0;
    if (f < 2816) {
        in = aw; out = awt; K = 1024; N = 3072;
        const int t = f - 2048;
        n0 = (t % 48) * 64; k0 = (t / 48) * 64;
    } else {
        in = pw; out = pwt; K = 1024; N = 1024;
        const int t = f - 2816;
        n0 = (t & 15) * 64; k0 = (t >> 4) * 64;
    }
    #pragma unroll
    for (int it = 0; it < 4; ++it) {
        int idx = tid + it * 256;
        int r = idx >> 4, c4 = (idx & 15) * 4;
        float4 v = *(const float4*)&in[(size_t)(k0 + r) * N + n0 + c4];
        tl[r][c4 + 0] = f2bf(v.x); tl[r][c4 + 1] = f2bf(v.y);
        tl[r][c4 + 2] = f2bf(v.z); tl[r][c4 + 3] = f2bf(v.w);
    }
    __syncthreads();
    #pragma unroll
    for (int it = 0; it < 4; ++it) {
        int idx = tid + it * 256;
        int r = idx >> 4, c4 = (idx & 15) * 4;
        ushort4 v;
        v.x = tl[c4 + 0][r]; v.y = tl[c4 + 1][r];
        v.z = tl[c4 + 2][r]; v.w = tl[c4 + 3][r];
        *(ushort4*)&out[(size_t)(n0 + r) * K + k0 + c4] = v;
    }
}

// ---------------------------------------------------------------------------
// QKV GEMM, 2-phase double-buffered: C = x @ c_attn_w^T + bias.
// K and Q bands (coln < 2048) -> kq COMPACT [4096][2048] (V band not stored).
// V band (coln >= 2048) -> vtr [BH][64][2048] TRANSPOSED DIRECTLY:
// acc rows r=0..3 are 4 consecutive t -> one ushort4 store per (mt,nt).
// Branch on coln>=2048 is wave-uniform. BM=BN=128, BK=32, 4 waves 2x2;
// glds16 prefetch next K-tile BEFORE compute, ONE barrier/iter; LDS chunk
// swizzle (pre-swizzled source, rule 21). K cols (<1024) pre-scaled by
// log2(e)/sqrt(64). LDS 32 KB -> 3 blocks/CU.
// ---------------------------------------------------------------------------
__global__ __launch_bounds__(256) void gemm_qkv(const u16* __restrict__ A,
                                                const u16* __restrict__ BT,
                                                const float* __restrict__ bias,
                                                u16* __restrict__ out,
                                                u16* __restrict__ vtr) {
    __shared__ u16 As[2][128 * 32];
    __shared__ u16 Bs[2][128 * 32];
    const int tid = threadIdx.x;
    const int w = tid >> 6, lane = tid & 63;
    const int c = lane & 15, qd = lane >> 4;
    const int wm = (w >> 1) * 64, wn = (w & 1) * 64;
    const int bm = blockIdx.x * 128, bn = blockIdx.y * 128;
    const int K = 1024;

    f32x4 acc[4][4];
    #pragma unroll
    for (int mt = 0; mt < 4; ++mt)
        #pragma unroll
        for (int nt = 0; nt < 4; ++nt)
            acc[mt][nt] = (f32x4){0.f, 0.f, 0.f, 0.f};

    // staging: thread -> (row = tid>>2 [+64], src chunk swizzled by (row>>1)&3)
    const int srow = tid >> 2;
    const int schk8 = ((tid & 3) ^ ((tid >> 3) & 3)) * 8;
    const u16* aP = A + (size_t)(bm + srow) * K + schk8;
    const u16* bP = BT + (size_t)(bn + srow) * K + schk8;
    const int rk = (c >> 1) & 3;          // read-side xor key

    // prologue: stage K-tile 0 into buffer 0
    glds16(aP, &As[0][tid * 8]);
    glds16(aP + 64 * K, &As[0][2048 + tid * 8]);
    glds16(bP, &Bs[0][tid * 8]);
    glds16(bP + 64 * K, &Bs[0][2048 + tid * 8]);
    __syncthreads();

    for (int kk = 0; kk < K; kk += 32) {
        const int cur = (kk >> 5) & 1;
        if (kk + 32 < K) {               // prefetch next K-tile into other buf
            const int nb = cur ^ 1;
            glds16(aP + kk + 32, &As[nb][tid * 8]);
            glds16(aP + kk + 32 + 64 * K, &As[nb][2048 + tid * 8]);
            glds16(bP + kk + 32, &Bs[nb][tid * 8]);
            glds16(bP + kk + 32 + 64 * K, &Bs[nb][2048 + tid * 8]);
        }
        bf16x8 af[4], bfr[4];
        #pragma unroll
        for (int mt = 0; mt < 4; ++mt)
            af[mt] = *(const bf16x8*)&As[cur][(wm + mt * 16 + c) * 32 + ((qd ^ rk) << 3)];
        #pragma unroll
        for (int nt = 0; nt < 4; ++nt)
            bfr[nt] = *(const bf16x8*)&Bs[cur][(wn + nt * 16 + c) * 32 + ((qd ^ rk) << 3)];
        #pragma unroll
        for (int mt = 0; mt < 4; ++mt)
            #pragma unroll
            for (int nt = 0; nt < 4; ++nt)
                acc[mt][nt] = MFMA_BF16(af[mt], bfr[nt], acc[mt][nt]);
        __syncthreads();                 // drains prefetch vmcnt + read lgkm
    }

    #pragma unroll
    for (int nt = 0; nt < 4; ++nt) {
        const int coln = bn + wn + nt * 16 + c;
        const float bv = bias[coln];
        if (coln < 2048) {
            // K band pre-scaled by log2(e)/sqrt(64); Q band natural
            const float kscl = (coln < 1024) ? 0.18033688f : 1.0f;
            #pragma unroll
            for (int mt = 0; mt < 4; ++mt)
                #pragma unroll
                for (int r = 0; r < 4; ++r) {
                    const int row = bm + wm + mt * 16 + qd * 4 + r;
                    out[(size_t)row * 2048 + coln] = f2bf((acc[mt][nt][r] + bv) * kscl);
                }
        } else {
            // V band: write transposed directly into vtr[bh][dd][t]
            const int hh = (coln - 2048) >> 6;
            const int dd = coln & 63;
            #pragma unroll
            for (int mt = 0; mt < 4; ++mt) {
                const int row0 = bm + wm + mt * 16 + qd * 4;
                const int bb = row0 >> 11, t0 = row0 & 2047;
                ushort4 st;
                st.x = f2bf(acc[mt][nt][0] + bv);
                st.y = f2bf(acc[mt][nt][1] + bv);
                st.z = f2bf(acc[mt][nt][2] + bv);
                st.w = f2bf(acc[mt][nt][3] + bv);
                *(ushort4*)&vtr[((size_t)(bb * 16 + hh) * 64 + dd) * 2048 + t0] = st;
            }
        }
    }
}

// ---------------------------------------------------------------------------
// Proj GEMM: C[4096,1024] f32 = A[4096,1024]*BT[1024,1024]^T + bias.
// BM=128, BN=64 -> grid 32x16 = 512 blocks. 4 waves 4Mx1N. LDS 24 KB.
// ---------------------------------------------------------------------------
__global__ __launch_bounds__(256) void gemm_proj(const u16* __restrict__ A,
                                                 const u16* __restrict__ BT,
                                                 const float* __restrict__ bias,
                                                 float* __restrict__ outf) {
    __shared__ u16 As[2][128 * 32];
    __shared__ u16 Bs[2][64 * 32];
    const int tid = threadIdx.x;
    const int w = tid >> 6, lane = tid & 63;
    const int c = lane & 15, qd = lane >> 4;
    const int wm = w * 32;
    const int bm = blockIdx.x * 128, bn = blockIdx.y * 64;
    const int K = 1024;

    f32x4 acc[2][4];
    #pragma unroll
    for (int mt = 0; mt < 2; ++mt)
        #pragma unroll
        for (int nt = 0; nt < 4; ++nt)
            acc[mt][nt] = (f32x4){0.f, 0.f, 0.f, 0.f};

    const int srow = tid >> 2;
    const int schk8 = ((tid & 3) ^ ((tid >> 3) & 3)) * 8;
    const u16* aP = A + (size_t)(bm + srow) * K + schk8;
    const u16* bP = BT + (size_t)(bn + srow) * K + schk8;
    const int rk = (c >> 1) & 3;

    glds16(aP, &As[0][tid * 8]);
    glds16(aP + 64 * K, &As[0][2048 + tid * 8]);
    glds16(bP, &Bs[0][tid * 8]);
    __syncthreads();

    for (int kk = 0; kk < K; kk += 32) {
        const int cur = (kk >> 5) & 1;
        if (kk + 32 < K) {
            const int nb = cur ^ 1;
            glds16(aP + kk + 32, &As[nb][tid * 8]);
            glds16(aP + kk + 32 + 64 * K, &As[nb][2048 + tid * 8]);
            glds16(bP + kk + 32, &Bs[nb][tid * 8]);
        }
        bf16x8 af[2], bfr[4];
        #pragma unroll
        for (int mt = 0; mt < 2; ++mt)
            af[mt] = *(const bf16x8*)&As[cur][(wm + mt * 16 + c) * 32 + ((qd ^ rk) << 3)];
        #pragma unroll
        for (int nt = 0; nt < 4; ++nt)
            bfr[nt] = *(const bf16x8*)&Bs[cur][(nt * 16 + c) * 32 + ((qd ^ rk) << 3)];
        #pragma unroll
        for (int mt = 0; mt < 2; ++mt)
            #pragma unroll
            for (int nt = 0; nt < 4; ++nt)
                acc[mt][nt] = MFMA_BF16(af[mt], bfr[nt], acc[mt][nt]);
        __syncthreads();
    }

    #pragma unroll
    for (int nt = 0; nt < 4; ++nt) {
        const int coln = bn + nt * 16 + c;
        const float bv = bias[coln];
        #pragma unroll
        for (int mt = 0; mt < 2; ++mt)
            #pragma unroll
            for (int r = 0; r < 4; ++r) {
                const int row = bm + wm + mt * 16 + qd * 4 + r;
                outf[(size_t)row * 1024 + coln] = acc[mt][nt][r] + bv;
            }
    }
}

// ---------------------------------------------------------------------------
// MFMA flash attention (v6 structure, best measured 43.0-43.3us; REVERTED
// from v13's PV-lag pipeline which measured 46.0us — PV serialization was
// not the binding chain; the extra LDS (50.7KB) and buffer logic cost more
// than the overlap gained. This kernel is a verified local optimum:
// occupancy-add (r5), P-in-regs (r6), Q-in-regs (r4/7/8), PV-lag (r13)
// all tested null or negative).
// Reads K/Q from COMPACT kq [4096][2048] (stride 2048; K band cols 0..1023,
// Q band 1024..2047). 1024 blocks (32 ib x 32 bh), one 64-row i-block per
// block, longest-first. 3 blocks/CU (LDS 42.5KB). P pack via
// round-half-up + v_perm. XCD-grouped bh decode; Q/V dbuf glds16;
// XOR-swizzled [64][64] LDS; K-frags direct global->regs; static-max
// softmax; l_lane + shfl epilogue.
// ---------------------------------------------------------------------------
__global__ __launch_bounds__(256, 3) void attn_kernel(const u16* __restrict__ kq,
                                                      const u16* __restrict__ vtbuf,
                                                      u16* __restrict__ outb) {
    __shared__ __align__(16) u16 Qb[2][64 * 64];
    __shared__ __align__(16) u16 Vb[2][64 * 64];
    __shared__ __align__(16) u16 Ps[4][16 * 72];
    __shared__ float red[4][16];

    const int tid = threadIdx.x;
    const int w = tid >> 6, lane = tid & 63;
    const int c = lane & 15, qd = lane >> 4;
    // decode: xcd = f&7 hosts bh in [xcd*4, xcd*4+4); ib descending in time
    const int f = blockIdx.x;
    const int bh = (f & 7) * 4 + ((f >> 3) & 3);
    const int ib = 31 - (f >> 5);       // longest blocks dispatch first
    const int b = bh >> 4, hh = bh & 15;
    const u16* kp = kq + (size_t)b * 2048 * 2048 + hh * 64;          // k band
    const u16* qp = kq + (size_t)b * 2048 * 2048 + 1024 + hh * 64;   // q band
    const u16* vp = vtbuf + (size_t)bh * (64 * 2048);
    u16* op = outb + (size_t)b * (2048 * 1024) + hh * 64;
    const f32x4 zero4 = {0.f, 0.f, 0.f, 0.f};

    // staging geometry: thread covers slots (w*128+lane) and (+64); 8 rows/8 col8
    const int slot0 = w * 128 + lane;
    const int slot1 = slot0 + 64;
    const int r0 = slot0 >> 3, r1 = slot1 >> 3;            // r1 = r0 + 8
    const int c8g = ((lane & 7) ^ ((lane >> 3) & 7)) * 8;  // swizzled src col
    const int swz = (c & 7);                               // read-side xor key

    const int nj = ib + 1;
    const int iw = ib * 64 + w * 16;                       // wave's 16 i-rows

    // K fragments direct from global (2 KB/wave, read once per block)
    bf16x8 kf[2];
    #pragma unroll
    for (int kt = 0; kt < 2; ++kt)
        kf[kt] = *(const bf16x8*)&kp[(size_t)(iw + c) * 2048 + kt * 32 + qd * 8];

    f32x4 oacc[4];
    #pragma unroll
    for (int nt = 0; nt < 4; ++nt)
        oacc[nt] = zero4;
    float l_lane = 0.f;

    // prologue: stage tile 0 into buffer 0
    glds16(qp + (size_t)r0 * 2048 + c8g, &Qb[0][slot0 * 8]);
    glds16(qp + (size_t)r1 * 2048 + c8g, &Qb[0][slot1 * 8]);
    glds16(vp + (size_t)r0 * 2048 + c8g, &Vb[0][slot0 * 8]);
    glds16(vp + (size_t)r1 * 2048 + c8g, &Vb[0][slot1 * 8]);
    __syncthreads();

    for (int jj = 0; jj < nj; ++jj) {
        const int cur = jj & 1;
        if (jj + 1 < nj) {              // async-prefetch next tile
            const int jn = (jj + 1) * 64;
            const int nb = cur ^ 1;
            glds16(qp + (size_t)(jn + r0) * 2048 + c8g, &Qb[nb][slot0 * 8]);
            glds16(qp + (size_t)(jn + r1) * 2048 + c8g, &Qb[nb][slot1 * 8]);
            glds16(vp + (size_t)r0 * 2048 + jn + c8g, &Vb[nb][slot0 * 8]);
            glds16(vp + (size_t)r1 * 2048 + jn + c8g, &Vb[nb][slot1 * 8]);
        }
        const int j0 = jj * 64;

        // S^T[j][i]: A = Q rows j (4 jt), B = kf (wave's 16 i-rows)
        bf16x8 qf[4][2];
        #pragma unroll
        for (int jt = 0; jt < 4; ++jt)
            #pragma unroll
            for (int kt = 0; kt < 2; ++kt)
                qf[jt][kt] = *(const bf16x8*)&Qb[cur][(jt * 16 + c) * 64 + (((kt * 4 + qd) ^ swz) << 3)];
        f32x4 sacc[4];
        #pragma unroll
        for (int jt = 0; jt < 4; ++jt) {
            f32x4 s0 = zero4;
            s0 = MFMA_BF16(qf[jt][0], kf[0], s0);
            s0 = MFMA_BF16(qf[jt][1], kf[1], s0);
            sacc[jt] = s0;
        }

        if (j0 + 63 > iw) {   // causal: valid iff j <= i
            #pragma unroll
            for (int jt = 0; jt < 4; ++jt)
                #pragma unroll
                for (int r = 0; r < 4; ++r) {
                    int j = j0 + jt * 16 + qd * 4 + r;
                    int i = iw + c;
                    if (j > i) sacc[jt][r] = -3.0e38f;
                }
        }

        // static-max softmax; pack P via round-half-up + v_perm (3 ops / 2 vals)
        #pragma unroll
        for (int jt = 0; jt < 4; ++jt) {
            float p0 = exp2f(sacc[jt][0]);
            float p1 = exp2f(sacc[jt][1]);
            float p2 = exp2f(sacc[jt][2]);
            float p3 = exp2f(sacc[jt][3]);
            l_lane += (p0 + p1) + (p2 + p3);
            u32 b0, b1, b2, b3;
            __builtin_memcpy(&b0, &p0, 4);
            __builtin_memcpy(&b1, &p1, 4);
            __builtin_memcpy(&b2, &p2, 4);
            __builtin_memcpy(&b3, &p3, 4);
            uint2 pk;
            pk.x = __builtin_amdgcn_perm(b1 + 0x8000u, b0 + 0x8000u, 0x07060302u);
            pk.y = __builtin_amdgcn_perm(b3 + 0x8000u, b2 + 0x8000u, 0x07060302u);
            *(uint2*)&Ps[w][c * 72 + jt * 16 + qd * 4] = pk;
        }

        // O[i][d] += P[i][j] * V[j][d]
        #pragma unroll
        for (int kt = 0; kt < 2; ++kt) {
            bf16x8 pf = *(const bf16x8*)&Ps[w][c * 72 + kt * 32 + qd * 8];
            #pragma unroll
            for (int nt = 0; nt < 4; ++nt) {
                bf16x8 vf = *(const bf16x8*)&Vb[cur][(nt * 16 + c) * 64 + (((kt * 4 + qd) ^ swz) << 3)];
                oacc[nt] = MFMA_BF16(pf, vf, oacc[nt]);
            }
        }
        __syncthreads();   // drains prefetch glds; all reads of cur done
    }

    // epilogue: reduce l over qd, redistribute per-row, write out
    float l = l_lane;
    l += __shfl_xor(l, 16);
    l += __shfl_xor(l, 32);
    red[w][c] = l;
    #pragma unroll
    for (int r = 0; r < 4; ++r) {
        const int irow = iw + qd * 4 + r;
        const float inv = 1.0f / red[w][qd * 4 + r];
        #pragma unroll
        for (int nt = 0; nt < 4; ++nt)
            op[(size_t)irow * 1024 + nt * 16 + c] = f2bf(oacc[nt][r] * inv);
    }
}

// ---------------------------------------------------------------------------
// ws plan (peak 34 MiB, ALL LIFETIMES DISJOINT):
//   kq@0       16M  [4096][2048] bf16 (K+Q compact)   live gemm_qkv -> attn
//   vtr@16M     8M  [BH][64][2048]                    live gemm_qkv -> attn
//   wt_attn@24M 6M                                    live prep -> gemm_qkv
//   abuf@24M    8M  (overlaps wt_attn AFTER it's dead) live attn -> gemm_proj
//   wt_proj@32M 2M  (own slot, untouched in between)  live prep -> gemm_proj
//   xb (bf16 x) staged in d_out (16 MB f32 out); dead before gemm_proj.
// ---------------------------------------------------------------------------
extern "C" void kernel_launch(void* const* d_in, const int* in_sizes, int n_in,
                              void* d_out, int out_size, void* d_ws, size_t ws_size,
                              hipStream_t stream) {
    const void *px = nullptr, *paw = nullptr, *pab = nullptr, *ppw = nullptr, *ppb = nullptr;
    for (int i = 0; i < n_in; ++i) {
        switch (in_sizes[i]) {
            case 4194304: px  = d_in[i]; break;  // x [2,2048,1024] f32
            case 3145728: paw = d_in[i]; break;  // c_attn_w [1024,3072] f32
            case 3072:    pab = d_in[i]; break;  // c_attn_b f32
            case 1048576: ppw = d_in[i]; break;  // c_proj_w [1024,1024] f32
            case 1024:    ppb = d_in[i]; break;  // c_proj_b f32
        }
    }
    if (!px || !paw || !pab || !ppw || !ppb) return;

    char* ws = (char*)d_ws;
    u16* kq      = (u16*)(ws);                 // [4096,2048] bf16  16 MB
    u16* vtr     = (u16*)(ws + 16777216);      // [2,16,64,2048]     8 MB
    u16* wt_attn = (u16*)(ws + 25165824);      // [3072,1024]        6 MB
    u16* abuf    = (u16*)(ws + 25165824);      // [4096,1024] bf16   8 MB (wt_attn dead)
    u16* wt_proj = (u16*)(ws + 33554432);      // [1024,1024]        2 MB (own slot)
    float* out   = (float*)d_out;              // [4096,1024] f32
    u16* xb      = (u16*)d_out;                // bf16 x staged in d_out

    prep<<<3072, 256, 0, stream>>>((const float*)px, xb,
                                   (const float*)paw, wt_attn,
                                   (const float*)ppw, wt_proj);
    gemm_qkv<<<dim3(32, 24), 256, 0, stream>>>(xb, wt_attn, (const float*)pab, kq, vtr);
    attn_kernel<<<dim3(1024), 256, 0, stream>>>(kq, vtr, abuf);
    gemm_proj<<<dim3(32, 16), 256, 0, stream>>>(abuf, wt_proj, (const float*)ppb, out);
}